// Round 9
// baseline (339.718 us; speedup 1.0000x reference)
//
#include <hip/hip_runtime.h>

static constexpr int VD = 16;     // vertex feature dim
static constexpr int SD = 64;     // state dim
static constexpr int ED = 16;     // edge feature dim
static constexpr int RH = 10, RD = 32;
static constexpr int N_ITERS = 3;
static constexpr int PREP_N = 128*64 + 192*64 + 64*32 + 64*32;  // 24576

typedef __attribute__((ext_vector_type(8))) short short8;
typedef __attribute__((ext_vector_type(4))) float floatx4;

__device__ __forceinline__ float sigmoid_f(float x) {
    return 1.f / (1.f + __expf(-x));
}
__device__ __forceinline__ float tanh_f(float x) {
    x = fminf(fmaxf(x, -20.f), 20.f);
    float e = __expf(2.f * x);
    return (e - 1.f) / (e + 1.f);
}
__device__ __forceinline__ unsigned short f2bf(float x) {   // round-to-nearest-even
    unsigned u = __float_as_uint(x);
    unsigned r = (u + 0x7FFFu + ((u >> 16) & 1u)) >> 16;
    return (unsigned short)r;
}
__device__ __forceinline__ float bf2f(unsigned short s) {
    return __uint_as_float(((unsigned)s) << 16);
}

// Merged: one-time weight transposes (first PREP_N ids) + degree histogram (rest).
__global__ void prep_hist_kernel(const float* __restrict__ W_msg,
                                 const float* __restrict__ W_i, const float* __restrict__ W_h,
                                 const float* __restrict__ W_embed,
                                 unsigned short* __restrict__ WabT, unsigned short* __restrict__ WiT,
                                 unsigned short* __restrict__ WhT, unsigned short* __restrict__ W3T,
                                 unsigned short* __restrict__ WeT,
                                 const int* __restrict__ edge_dst, int* __restrict__ deg,
                                 int n_edges) {
    int gid = blockIdx.x * blockDim.x + threadIdx.x;
    int i = gid;
    if (i < 128*64) {                       // WabT[n][k]
        int n = i >> 6, k = i & 63;
        WabT[i] = f2bf(W_msg[((n < 64 ? 0 : 64) + k)*64 + (n & 63)]);
    }
    int j = i - 128*64;
    if (j >= 0 && j < 192*64) {             // WiT/WhT[n][k] = W[k][n]
        int n = j >> 6, k = j & 63;
        WiT[j] = f2bf(W_i[k*192 + n]);
        WhT[j] = f2bf(W_h[k*192 + n]);
    }
    int l = i - 128*64 - 192*64;
    if (l >= 0 && l < 64*32) {              // W3T[n][k], k padded 16->32
        int n = l >> 5, k = l & 31;
        W3T[l] = (k < 16) ? f2bf(W_msg[(128+k)*64 + n]) : (unsigned short)0;
    }
    int m = i - 128*64 - 192*64 - 64*32;
    if (m >= 0 && m < 64*32) {              // WeT[n][k], k padded 16->32
        int n = m >> 5, k = m & 31;
        WeT[m] = (k < 16) ? f2bf(W_embed[k*64 + n]) : (unsigned short)0;
    }
    int e = gid - PREP_N;
    if (e >= 0 && e < n_edges) atomicAdd(&deg[edge_dst[e]], 1);
}

// Exclusive scan of EVEN-PADDED degrees -> row_ptr; plus degree-bucket histogram
// and DESCENDING bucket bases (for the counting sort / LPT tile order).
__global__ __launch_bounds__(1024) void scan_kernel(const int* __restrict__ deg,
                                                    int* __restrict__ row_ptr,
                                                    int* __restrict__ bucket_base,
                                                    int n_nodes) {
    __shared__ int wsum[16];
    __shared__ int bh[128];
    int lid = threadIdx.x, lane = lid & 63, wv = lid >> 6;
    if (lid < 128) bh[lid] = 0;
    __syncthreads();
    int C = (n_nodes + 1023) >> 10;
    int start = lid * C;
    int lsum = 0;
    for (int i = 0; i < C; ++i) {
        int idx = start + i;
        if (idx < n_nodes) {
            int d = deg[idx];
            lsum += (d + 1) & ~1;
            atomicAdd(&bh[d < 127 ? d : 127], 1);
        }
    }
    int x = lsum;
    #pragma unroll
    for (int off = 1; off < 64; off <<= 1) {
        int y = __shfl_up(x, off);
        if (lane >= off) x += y;
    }
    if (lane == 63) wsum[wv] = x;
    __syncthreads();
    if (lid == 0) {                          // descending bucket scan (127 -> 0)
        int run = 0;
        for (int b = 127; b >= 0; --b) { bucket_base[b] = run; run += bh[b]; }
    }
    if (wv == 0 && lane < 16) {
        int t = wsum[lane];
        #pragma unroll
        for (int off = 1; off < 16; off <<= 1) {
            int y = __shfl_up(t, off);
            if (lane >= off) t += y;
        }
        wsum[lane] = t;
    }
    __syncthreads();
    int wbase = (wv > 0) ? wsum[wv - 1] : 0;
    int run = wbase + x - lsum;
    for (int i = 0; i < C; ++i) {
        int idx = start + i;
        if (idx < n_nodes) { row_ptr[idx] = run; run += (deg[idx] + 1) & ~1; }
    }
}

// Merged: CSR fill (edge range) + counting-sort scatter perm[slot]=node (node range).
__global__ void fill_scatter_kernel(const int* __restrict__ edge_dst,
                                    const int* __restrict__ row_ptr, int* __restrict__ fillc,
                                    int* __restrict__ eid,
                                    const int* __restrict__ deg, const int* __restrict__ bucket_base,
                                    int* __restrict__ bucket_fill, int* __restrict__ perm,
                                    int n_edges, int n_nodes) {
    int gid = blockIdx.x * blockDim.x + threadIdx.x;
    if (gid < n_edges) {
        int d = edge_dst[gid];
        int ofs = atomicAdd(&fillc[d], 1);
        eid[row_ptr[d] + ofs] = gid;
    }
    int n = gid - n_edges;
    if (n >= 0 && n < n_nodes) {
        int d = deg[n]; int b = d < 127 ? d : 127;
        int pos = atomicAdd(&bucket_fill[b], 1);
        perm[bucket_base[b] + pos] = n;
    }
}

// Once: Cp[pair][col] (uint: lo=even edge, hi=odd) = edge_data@W3 (bf16) + src_csr gather.
__global__ __launch_bounds__(256) void edgeconst_kernel(
        const int* __restrict__ eid, const int* __restrict__ edge_src,
        const float* __restrict__ edge_data, const unsigned short* __restrict__ W3T,
        int* __restrict__ src_csr, unsigned short* __restrict__ Cp, int Lmax) {
    int w = blockIdx.x * 4 + (threadIdx.x >> 6);
    int lane = threadIdx.x & 63;
    int e0 = w * 16;
    if (e0 >= Lmax) return;
    int quad = lane >> 4, l16 = lane & 15;
    int erow = e0 + l16;
    int ev = eid[erow];                      // coalesced; 0 for pads
    if (quad == 0) src_csr[erow] = edge_src[ev];
    short8 a0 = {0,0,0,0,0,0,0,0};
    if (quad < 2) {
        const float4* ep = (const float4*)(edge_data + (size_t)ev*ED + quad*8);
        float4 x0 = ep[0], x1 = ep[1];
        a0[0]=(short)f2bf(x0.x); a0[1]=(short)f2bf(x0.y); a0[2]=(short)f2bf(x0.z); a0[3]=(short)f2bf(x0.w);
        a0[4]=(short)f2bf(x1.x); a0[5]=(short)f2bf(x1.y); a0[6]=(short)f2bf(x1.z); a0[7]=(short)f2bf(x1.w);
    }
    floatx4 z4 = {0.f,0.f,0.f,0.f};
    #pragma unroll
    for (int nt = 0; nt < 4; ++nt) {
        int n = nt*16 + l16;
        short8 b0 = *(const short8*)(W3T + (size_t)n*32 + quad*8);
        floatx4 d = __builtin_amdgcn_mfma_f32_16x16x32_bf16(a0, b0, z4, 0, 0, 0);
        #pragma unroll
        for (int rp = 0; rp < 2; ++rp) {
            int e = e0 + quad*4 + 2*rp;
            unsigned pack = (unsigned)f2bf(d[2*rp]) | ((unsigned)f2bf(d[2*rp+1]) << 16);
            *(unsigned*)(Cp + (size_t)(e >> 1)*128 + n*2) = pack;
        }
    }
}

// Embed via MFMA + fused iter-0 [A|B]. Tiles over SLOTS (degree-sorted perm).
// hb/Ab are slot-indexed (coalesced); Bb node-indexed (for src gathers).
__global__ __launch_bounds__(256) void embed_fused_kernel(
        const float* __restrict__ node_data, const unsigned short* __restrict__ WeT,
        const float* __restrict__ b_embed, const int* __restrict__ perm,
        unsigned short* __restrict__ hb,
        const unsigned short* __restrict__ WabT, const float* __restrict__ b_msg,
        unsigned short* __restrict__ Ab, unsigned short* __restrict__ Bb, int n_nodes) {
    __shared__ unsigned short hs[16 * 68];
    int jt = threadIdx.x >> 6, lane = threadIdx.x & 63;
    int m0 = blockIdx.x * 16;
    if (m0 >= n_nodes) return;
    int quad = lane >> 4, l16 = lane & 15;
    int slot_l = m0 + l16; if (slot_l >= n_nodes) slot_l = n_nodes - 1;
    int real_l = perm[slot_l];
    short8 a0 = {0,0,0,0,0,0,0,0};
    if (quad < 2) {
        const float4* np = (const float4*)(node_data + (size_t)real_l*VD + quad*8);
        float4 x0 = np[0], x1 = np[1];
        a0[0]=(short)f2bf(x0.x); a0[1]=(short)f2bf(x0.y); a0[2]=(short)f2bf(x0.z); a0[3]=(short)f2bf(x0.w);
        a0[4]=(short)f2bf(x1.x); a0[5]=(short)f2bf(x1.y); a0[6]=(short)f2bf(x1.z); a0[7]=(short)f2bf(x1.w);
    }
    int j = jt*16 + l16;
    short8 b0 = *(const short8*)(WeT + (size_t)j*32 + quad*8);
    floatx4 z4 = {0.f,0.f,0.f,0.f};
    floatx4 d = __builtin_amdgcn_mfma_f32_16x16x32_bf16(a0, b0, z4, 0, 0, 0);
    float bias = b_embed[j];
    #pragma unroll
    for (int r = 0; r < 4; ++r) {
        int slot = m0 + quad*4 + r;
        unsigned short v16 = f2bf(d[r] + bias);
        hs[(quad*4 + r)*68 + j] = v16;
        if (slot < n_nodes) hb[(size_t)slot*SD + j] = v16;   // slot-indexed
    }
    __syncthreads();
    short8 aa0 = *(const short8*)(hs + l16*68 + quad*8);
    short8 aa1 = *(const short8*)(hs + l16*68 + 32 + quad*8);
    #pragma unroll
    for (int s = 0; s < 2; ++s) {
        int ncol = (jt + 4*s)*16 + l16;
        const short8* bp = (const short8*)(WabT + (size_t)ncol*SD + quad*8);
        floatx4 dd = __builtin_amdgcn_mfma_f32_16x16x32_bf16(aa0, bp[0], z4, 0, 0, 0);
        dd = __builtin_amdgcn_mfma_f32_16x16x32_bf16(aa1, bp[4], dd, 0, 0, 0);
        float bias2 = (s == 0) ? b_msg[ncol] : 0.f;
        int jc = jt*16 + l16;
        #pragma unroll
        for (int r = 0; r < 4; ++r) {
            int slot = m0 + quad*4 + r;
            if (slot >= n_nodes) break;
            float v = dd[r] + bias2;
            if (s == 0) Ab[(size_t)slot*SD + jc] = f2bf(v);          // slot-indexed
            else        Bb[(size_t)perm[slot]*SD + jc] = f2bf(v);    // node-indexed
        }
    }
}

// One full MPNN iteration. Block = 16-SLOT tile (degree-sorted), 4 waves.
template<int FIRST, int LAST>
__global__ __launch_bounds__(256) void mpnn_iter_kernel(
        const unsigned short* __restrict__ hbr, unsigned short* __restrict__ hbw,
        const unsigned short* __restrict__ Abr, const unsigned short* __restrict__ Bbr,
        unsigned short* __restrict__ Abw, unsigned short* __restrict__ Bbw,
        const unsigned short* __restrict__ Cp, const int* __restrict__ src_csr,
        const int* __restrict__ row_ptr, const int* __restrict__ deg,
        const int* __restrict__ perm,
        unsigned short* __restrict__ m_accb,
        const unsigned short* __restrict__ WiT, const unsigned short* __restrict__ WhT,
        const float* __restrict__ b_i, const float* __restrict__ b_h,
        const unsigned short* __restrict__ WabT, const float* __restrict__ b_msg,
        const float* __restrict__ W_r1, const float* __restrict__ b_r1,
        const float* __restrict__ W_r2, float* __restrict__ partials,
        int n_nodes) {
    __shared__ unsigned short hsm[16 * 68];   // m tile (bf16)
    __shared__ unsigned short hsn[16 * 68];   // hnew tile (bf16)
    int w = threadIdx.x >> 6, lane = threadIdx.x & 63;
    int m0 = blockIdx.x * 16;
    if (m0 >= n_nodes) return;

    // ---- Phase 1: aggregation, 4 slots per wave (near-equal degrees) ----
    int e0[4], dg[4], pend[4]; float aval[4], base[4];
    #pragma unroll
    for (int u = 0; u < 4; ++u) {
        int slot = m0 + w*4 + u;
        bool v = slot < n_nodes;
        int sc = v ? slot : n_nodes - 1;
        int real = perm[sc];
        e0[u] = row_ptr[real];
        dg[u] = v ? deg[real] : 0;
        int pairs = (dg[u] + 1) >> 1;
        pend[u] = (e0[u] >> 1) + (pairs > 0 ? pairs - 1 : 0);  // own last pair (no stray fetch)
        aval[u] = bf2f(Abr[(size_t)sc*SD + lane]);
        base[u] = FIRST ? 0.f : bf2f(m_accb[(size_t)sc*SD + lane]);
    }
    float acc[4] = {0.f, 0.f, 0.f, 0.f};
    int mx = max(max(dg[0], dg[1]), max(dg[2], dg[3]));
    for (int c = 0; c*16 < mx; ++c) {
        #pragma unroll
        for (int up = 0; up < 2; ++up) {
            int sv[2]; unsigned cp2[2][8]; float bv[2][16];
            #pragma unroll
            for (int q = 0; q < 2; ++q) {
                int u = up*2 + q;
                int ilast = e0[u] + (dg[u] > 0 ? dg[u] - 1 : 0);
                int i = e0[u] + c*16 + (lane & 15);
                if (i > ilast) i = ilast;
                sv[q] = src_csr[i];
                int pb = (e0[u] >> 1) + c*8;
                #pragma unroll
                for (int t2 = 0; t2 < 8; ++t2) {
                    int pi = pb + t2; if (pi > pend[u]) pi = pend[u];
                    cp2[q][t2] = *(const unsigned*)(Cp + (size_t)pi*128 + lane*2);
                }
            }
            #pragma unroll
            for (int q = 0; q < 2; ++q) {
                #pragma unroll
                for (int t = 0; t < 16; ++t) {
                    int s = __builtin_amdgcn_readlane(sv[q], t);
                    bv[q][t] = bf2f(Bbr[(size_t)s*SD + lane]);
                }
            }
            #pragma unroll
            for (int q = 0; q < 2; ++q) {
                int u = up*2 + q;
                int cnt = dg[u] - c*16;
                #pragma unroll
                for (int t = 0; t < 16; ++t) {
                    if (t < cnt) {
                        float cv = bf2f((unsigned short)((t & 1) ? (cp2[q][t>>1] >> 16)
                                                                 : (cp2[q][t>>1] & 0xFFFF)));
                        acc[u] += fmaxf(aval[u] + bv[q][t] + cv, 0.f);
                    }
                }
            }
        }
    }
    #pragma unroll
    for (int u = 0; u < 4; ++u) {
        int slot = m0 + w*4 + u;
        unsigned short nv16 = f2bf(base[u] + acc[u]);
        hsm[(w*4 + u)*68 + lane] = nv16;
        if (!LAST && slot < n_nodes) m_accb[(size_t)slot*SD + lane] = nv16;
    }
    __syncthreads();

    // ---- Phase 2: GRU via MFMA (slot-indexed hb: coalesced) ----
    int quad = lane >> 4, l16 = lane & 15;
    int srow = m0 + l16; if (srow >= n_nodes) srow = n_nodes - 1;
    const short8* hp = (const short8*)(hbr + (size_t)srow*SD + quad*8);
    short8 ha0 = hp[0], ha1 = hp[4];
    short8 ma0 = *(const short8*)(hsm + l16*68 + quad*8);
    short8 ma1 = *(const short8*)(hsm + l16*68 + 32 + quad*8);
    int j0 = w * 16;
    floatx4 di[3], dh[3];
    floatx4 z4 = {0.f,0.f,0.f,0.f};
    #pragma unroll
    for (int g = 0; g < 3; ++g) {
        int n = g*64 + j0 + l16;
        const short8* bi = (const short8*)(WiT + (size_t)n*SD + quad*8);
        const short8* bh = (const short8*)(WhT + (size_t)n*SD + quad*8);
        di[g] = __builtin_amdgcn_mfma_f32_16x16x32_bf16(ma0, bi[0], z4,    0, 0, 0);
        di[g] = __builtin_amdgcn_mfma_f32_16x16x32_bf16(ma1, bi[4], di[g], 0, 0, 0);
        dh[g] = __builtin_amdgcn_mfma_f32_16x16x32_bf16(ha0, bh[0], z4,    0, 0, 0);
        dh[g] = __builtin_amdgcn_mfma_f32_16x16x32_bf16(ha1, bh[4], dh[g], 0, 0, 0);
    }
    int j = j0 + l16;
    float bir = b_i[j], biz = b_i[64+j], bin = b_i[128+j];
    float bhr = b_h[j], bhz = b_h[64+j], bhn = b_h[128+j];
    #pragma unroll
    for (int r = 0; r < 4; ++r) {
        int slot = m0 + quad*4 + r;
        int sc = slot < n_nodes ? slot : n_nodes - 1;
        float rg = sigmoid_f(di[0][r] + bir + dh[0][r] + bhr);
        float zg = sigmoid_f(di[1][r] + biz + dh[1][r] + bhz);
        float ng = tanh_f(di[2][r] + bin + rg * (dh[2][r] + bhn));
        float hold = bf2f(hbr[(size_t)sc*SD + j]);
        float hnew = (1.f - zg) * ng + zg * hold;
        unsigned short hb16 = f2bf(hnew);
        hsn[(quad*4 + r)*68 + j] = hb16;
        if (!LAST && slot < n_nodes) hbw[(size_t)slot*SD + j] = hb16;
    }

    if (!LAST) {
        // ---- Phase 3a: next iteration's [A|B] ----
        __syncthreads();
        short8 a0 = *(const short8*)(hsn + l16*68 + quad*8);
        short8 a1 = *(const short8*)(hsn + l16*68 + 32 + quad*8);
        #pragma unroll
        for (int s = 0; s < 2; ++s) {
            int ncol = (w + 4*s)*16 + l16;
            const short8* bp = (const short8*)(WabT + (size_t)ncol*SD + quad*8);
            floatx4 d = __builtin_amdgcn_mfma_f32_16x16x32_bf16(a0, bp[0], z4, 0, 0, 0);
            d = __builtin_amdgcn_mfma_f32_16x16x32_bf16(a1, bp[4], d, 0, 0, 0);
            float bias = (s == 0) ? b_msg[ncol] : 0.f;
            int jc = w*16 + l16;
            #pragma unroll
            for (int r = 0; r < 4; ++r) {
                int slot = m0 + quad*4 + r;
                if (slot >= n_nodes) break;
                float v = d[r] + bias;
                if (s == 0) Abw[(size_t)slot*SD + jc] = f2bf(v);        // slot-indexed
                else        Bbw[(size_t)perm[slot]*SD + jc] = f2bf(v);  // node-indexed
            }
        }
    } else {
        // ---- Phase 3b: fused readout partials ----
        __syncthreads();
        __shared__ float ts[16 * 12];
        __shared__ float po[512];
        int tid = threadIdx.x;
        if (tid < 16 * RH) {
            int node = tid / RH, i = tid - node * RH;
            float a = b_r1[i];
            #pragma unroll 8
            for (int k = 0; k < SD; ++k)
                a += bf2f(hsn[node*68 + k]) * W_r1[k*RH + i];
            ts[node*12 + i] = fmaxf(a, 0.f);
        }
        __syncthreads();
        #pragma unroll
        for (int s = 0; s < 2; ++s) {
            int task = tid + s*256;
            int node = task >> 5, c = task & 31;
            float v = 0.f;
            if (m0 + node < n_nodes) {
                #pragma unroll
                for (int i = 0; i < RH; ++i) v += ts[node*12 + i] * W_r2[i*RD + c];
            }
            po[task] = v;
        }
        __syncthreads();
        if (tid < RD) {
            float s2 = 0.f;
            #pragma unroll
            for (int n = 0; n < 16; ++n) s2 += po[n*32 + tid];
            partials[(size_t)blockIdx.x * RD + tid] = s2;
        }
    }
}

// Final: out[c] = sum over blocks of partials + n_nodes * b_r2[c]. One block.
__global__ __launch_bounds__(1024) void final_sum_kernel(
        const float* __restrict__ partials, const float* __restrict__ b_r2,
        float* __restrict__ out, int mtiles, int n_nodes) {
    __shared__ float red[1024];
    int c = threadIdx.x & 31, g = threadIdx.x >> 5;
    float s = 0.f;
    for (int t = g; t < mtiles; t += 32) s += partials[(size_t)t*RD + c];
    red[threadIdx.x] = s;
    __syncthreads();
    #pragma unroll
    for (int off = 512; off >= 32; off >>= 1) {
        if ((int)threadIdx.x < off) red[threadIdx.x] += red[threadIdx.x + off];
        __syncthreads();
    }
    if (threadIdx.x < RD) out[threadIdx.x] = red[threadIdx.x] + (float)n_nodes * b_r2[threadIdx.x];
}

extern "C" void kernel_launch(void* const* d_in, const int* in_sizes, int n_in,
                              void* d_out, int out_size, void* d_ws, size_t ws_size,
                              hipStream_t stream) {
    const float* node_data = (const float*)d_in[0];
    const float* edge_data = (const float*)d_in[1];
    const int*   edge_src  = (const int*)d_in[2];
    const int*   edge_dst  = (const int*)d_in[3];
    const float* W_embed   = (const float*)d_in[4];
    const float* b_embed   = (const float*)d_in[5];
    const float* W_msg     = (const float*)d_in[6];
    const float* b_msg     = (const float*)d_in[7];
    const float* W_i       = (const float*)d_in[8];
    const float* b_i       = (const float*)d_in[9];
    const float* W_h       = (const float*)d_in[10];
    const float* b_h       = (const float*)d_in[11];
    const float* W_r1      = (const float*)d_in[12];
    const float* b_r1      = (const float*)d_in[13];
    const float* W_r2      = (const float*)d_in[14];
    const float* b_r2      = (const float*)d_in[15];

    int n_nodes = in_sizes[0] / VD;    // 20000
    int n_edges = in_sizes[2];         // 320000
    int Lmax = n_edges + n_nodes + 64; // padded CSR capacity
    int mtiles = (n_nodes + 15) / 16;

    char* ws = (char*)d_ws;
    size_t off = 0;
    auto alloc = [&](size_t bytes) {
        void* p = ws + off;
        off = (off + bytes + 255) & ~(size_t)255;
        return p;
    };
    unsigned short* m_accb = (unsigned short*)alloc((size_t)n_nodes * SD * 2);
    unsigned short* hbA = (unsigned short*)alloc((size_t)n_nodes * SD * 2);
    unsigned short* hbB = (unsigned short*)alloc((size_t)n_nodes * SD * 2);
    unsigned short* Ab0 = (unsigned short*)alloc((size_t)n_nodes * SD * 2);
    unsigned short* Bb0 = (unsigned short*)alloc((size_t)n_nodes * SD * 2);
    unsigned short* Ab1 = (unsigned short*)alloc((size_t)n_nodes * SD * 2);
    unsigned short* Bb1 = (unsigned short*)alloc((size_t)n_nodes * SD * 2);
    unsigned short* Cp  = (unsigned short*)alloc((size_t)(Lmax + 32) * SD * 2);
    int*   src_csr      = (int*)alloc((size_t)(Lmax + 32) * sizeof(int));
    int*   row_ptr      = (int*)alloc((size_t)(n_nodes + 1) * sizeof(int));
    int*   perm         = (int*)alloc((size_t)n_nodes * sizeof(int));
    int*   bucket_base  = (int*)alloc(128 * sizeof(int));
    float* partials     = (float*)alloc((size_t)mtiles * RD * sizeof(float));
    // contiguous zero-init region: deg, fillc, bucket_fill, eid (one memset)
    char*  zbase        = (char*)alloc(0);
    int*   deg          = (int*)alloc((size_t)n_nodes * sizeof(int));
    int*   fillc        = (int*)alloc((size_t)n_nodes * sizeof(int));
    int*   bucket_fill  = (int*)alloc(128 * sizeof(int));
    int*   eid          = (int*)alloc((size_t)(Lmax + 32) * sizeof(int));
    char*  zend         = (char*)alloc(0);
    unsigned short* WabT = (unsigned short*)alloc(128*64*2);
    unsigned short* WiT  = (unsigned short*)alloc(192*64*2);
    unsigned short* WhT  = (unsigned short*)alloc(192*64*2);
    unsigned short* W3T  = (unsigned short*)alloc(64*32*2);
    unsigned short* WeT  = (unsigned short*)alloc(64*32*2);
    (void)ws_size; (void)n_in;

    hipMemsetAsync(zbase, 0, (size_t)(zend - zbase), stream);

    prep_hist_kernel<<<(PREP_N + n_edges + 255)/256, 256, 0, stream>>>(
        W_msg, W_i, W_h, W_embed, WabT, WiT, WhT, W3T, WeT, edge_dst, deg, n_edges);

    scan_kernel<<<1, 1024, 0, stream>>>(deg, row_ptr, bucket_base, n_nodes);

    fill_scatter_kernel<<<(n_edges + n_nodes + 255)/256, 256, 0, stream>>>(
        edge_dst, row_ptr, fillc, eid, deg, bucket_base, bucket_fill, perm, n_edges, n_nodes);

    int ec_waves = (Lmax + 15) / 16;
    edgeconst_kernel<<<(ec_waves + 3)/4, 256, 0, stream>>>(eid, edge_src, edge_data, W3T,
                                                           src_csr, Cp, Lmax);

    embed_fused_kernel<<<mtiles, 256, 0, stream>>>(node_data, WeT, b_embed, perm, hbA,
                                                   WabT, b_msg, Ab0, Bb0, n_nodes);

    // it0: read Ab0/Bb0, hbA -> hbB, write Ab1/Bb1
    mpnn_iter_kernel<1,0><<<mtiles, 256, 0, stream>>>(hbA, hbB, Ab0, Bb0, Ab1, Bb1,
        Cp, src_csr, row_ptr, deg, perm, m_accb, WiT, WhT, b_i, b_h, WabT, b_msg,
        W_r1, b_r1, W_r2, partials, n_nodes);
    // it1: read Ab1/Bb1, hbB -> hbA, write Ab0/Bb0
    mpnn_iter_kernel<0,0><<<mtiles, 256, 0, stream>>>(hbB, hbA, Ab1, Bb1, Ab0, Bb0,
        Cp, src_csr, row_ptr, deg, perm, m_accb, WiT, WhT, b_i, b_h, WabT, b_msg,
        W_r1, b_r1, W_r2, partials, n_nodes);
    // it2 (LAST): fused readout partials
    mpnn_iter_kernel<0,1><<<mtiles, 256, 0, stream>>>(hbA, hbB, Ab0, Bb0, Ab1, Bb1,
        Cp, src_csr, row_ptr, deg, perm, m_accb, WiT, WhT, b_i, b_h, WabT, b_msg,
        W_r1, b_r1, W_r2, partials, n_nodes);

    final_sum_kernel<<<1, 1024, 0, stream>>>(partials, b_r2, (float*)d_out, mtiles, n_nodes);
}

// Round 10
// 302.321 us; speedup vs baseline: 1.1237x; 1.1237x over previous
//
#include <hip/hip_runtime.h>

static constexpr int VD = 16;     // vertex feature dim
static constexpr int SD = 64;     // state dim
static constexpr int ED = 16;     // edge feature dim
static constexpr int RH = 10, RD = 32;
static constexpr int N_ITERS = 3;
static constexpr int PREP_N = 128*64 + 192*64 + 64*32 + 64*32;  // 24576

typedef __attribute__((ext_vector_type(8))) short short8;
typedef __attribute__((ext_vector_type(4))) float floatx4;

__device__ __forceinline__ float sigmoid_f(float x) {
    return 1.f / (1.f + __expf(-x));
}
__device__ __forceinline__ float tanh_f(float x) {
    x = fminf(fmaxf(x, -20.f), 20.f);
    float e = __expf(2.f * x);
    return (e - 1.f) / (e + 1.f);
}
__device__ __forceinline__ unsigned short f2bf(float x) {   // round-to-nearest-even
    unsigned u = __float_as_uint(x);
    unsigned r = (u + 0x7FFFu + ((u >> 16) & 1u)) >> 16;
    return (unsigned short)r;
}
__device__ __forceinline__ float bf2f(unsigned short s) {
    return __uint_as_float(((unsigned)s) << 16);
}

// Merged: one-time weight transposes (first PREP_N ids) + degree histogram (rest).
__global__ void prep_hist_kernel(const float* __restrict__ W_msg,
                                 const float* __restrict__ W_i, const float* __restrict__ W_h,
                                 const float* __restrict__ W_embed,
                                 unsigned short* __restrict__ WabT, unsigned short* __restrict__ WiT,
                                 unsigned short* __restrict__ WhT, unsigned short* __restrict__ W3T,
                                 unsigned short* __restrict__ WeT,
                                 const int* __restrict__ edge_dst, int* __restrict__ deg,
                                 int n_edges) {
    int gid = blockIdx.x * blockDim.x + threadIdx.x;
    int i = gid;
    if (i < 128*64) {                       // WabT[n][k]
        int n = i >> 6, k = i & 63;
        WabT[i] = f2bf(W_msg[((n < 64 ? 0 : 64) + k)*64 + (n & 63)]);
    }
    int j = i - 128*64;
    if (j >= 0 && j < 192*64) {             // WiT/WhT[n][k] = W[k][n]
        int n = j >> 6, k = j & 63;
        WiT[j] = f2bf(W_i[k*192 + n]);
        WhT[j] = f2bf(W_h[k*192 + n]);
    }
    int l = i - 128*64 - 192*64;
    if (l >= 0 && l < 64*32) {              // W3T[n][k], k padded 16->32
        int n = l >> 5, k = l & 31;
        W3T[l] = (k < 16) ? f2bf(W_msg[(128+k)*64 + n]) : (unsigned short)0;
    }
    int m = i - 128*64 - 192*64 - 64*32;
    if (m >= 0 && m < 64*32) {              // WeT[n][k], k padded 16->32
        int n = m >> 5, k = m & 31;
        WeT[m] = (k < 16) ? f2bf(W_embed[k*64 + n]) : (unsigned short)0;
    }
    int e = gid - PREP_N;
    if (e >= 0 && e < n_edges) atomicAdd(&deg[edge_dst[e]], 1);
}

// Single block: (1) exclusive scan of EVEN-PADDED degrees -> row_ptr,
// (2) degree-bucket histogram + DESCENDING bases, (3) counting-sort scatter
// perm[slot]=node via LDS atomics (fast serialization vs L2 atomics).
__global__ __launch_bounds__(1024) void scan_kernel(const int* __restrict__ deg,
                                                    int* __restrict__ row_ptr,
                                                    int* __restrict__ perm,
                                                    int n_nodes) {
    __shared__ int wsum[16];
    __shared__ int bh[128];
    __shared__ int bbase[128];
    int lid = threadIdx.x, lane = lid & 63, wv = lid >> 6;
    if (lid < 128) bh[lid] = 0;
    __syncthreads();
    int C = (n_nodes + 1023) >> 10;
    int start = lid * C;
    int lsum = 0;
    for (int i = 0; i < C; ++i) {
        int idx = start + i;
        if (idx < n_nodes) {
            int d = deg[idx];
            lsum += (d + 1) & ~1;
            atomicAdd(&bh[d < 127 ? d : 127], 1);   // LDS atomic
        }
    }
    int x = lsum;
    #pragma unroll
    for (int off = 1; off < 64; off <<= 1) {
        int y = __shfl_up(x, off);
        if (lane >= off) x += y;
    }
    if (lane == 63) wsum[wv] = x;
    __syncthreads();                         // bh complete + wsum ready
    if (lid == 0) {                          // descending bucket scan (127 -> 0)
        int run = 0;
        for (int b = 127; b >= 0; --b) { bbase[b] = run; run += bh[b]; }
    }
    if (wv == 0 && lane < 16) {
        int t = wsum[lane];
        #pragma unroll
        for (int off = 1; off < 16; off <<= 1) {
            int y = __shfl_up(t, off);
            if (lane >= off) t += y;
        }
        wsum[lane] = t;
    }
    __syncthreads();                         // bbase + wsum scans done
    int wbase = (wv > 0) ? wsum[wv - 1] : 0;
    int run = wbase + x - lsum;
    for (int i = 0; i < C; ++i) {
        int idx = start + i;
        if (idx < n_nodes) {
            int d = deg[idx];
            row_ptr[idx] = run; run += (d + 1) & ~1;
            int b = d < 127 ? d : 127;
            int pos = atomicAdd(&bbase[b], 1);     // LDS atomic (running pointer)
            perm[pos] = idx;
        }
    }
}

// CSR fill: edges only (R8 form).
__global__ void fill_kernel(const int* __restrict__ edge_dst, const int* __restrict__ row_ptr,
                            int* __restrict__ fillc, int* __restrict__ eid, int n_edges) {
    for (int e = blockIdx.x*blockDim.x + threadIdx.x; e < n_edges; e += gridDim.x*blockDim.x) {
        int d = edge_dst[e];
        int ofs = atomicAdd(&fillc[d], 1);
        eid[row_ptr[d] + ofs] = e;
    }
}

// Once: Cp[pair][col] (uint: lo=even edge, hi=odd) = edge_data@W3 (bf16) + src_csr gather.
__global__ __launch_bounds__(256) void edgeconst_kernel(
        const int* __restrict__ eid, const int* __restrict__ edge_src,
        const float* __restrict__ edge_data, const unsigned short* __restrict__ W3T,
        int* __restrict__ src_csr, unsigned short* __restrict__ Cp, int Lmax) {
    int w = blockIdx.x * 4 + (threadIdx.x >> 6);
    int lane = threadIdx.x & 63;
    int e0 = w * 16;
    if (e0 >= Lmax) return;
    int quad = lane >> 4, l16 = lane & 15;
    int erow = e0 + l16;
    int ev = eid[erow];                      // coalesced; 0 for pads
    if (quad == 0) src_csr[erow] = edge_src[ev];
    short8 a0 = {0,0,0,0,0,0,0,0};
    if (quad < 2) {
        const float4* ep = (const float4*)(edge_data + (size_t)ev*ED + quad*8);
        float4 x0 = ep[0], x1 = ep[1];
        a0[0]=(short)f2bf(x0.x); a0[1]=(short)f2bf(x0.y); a0[2]=(short)f2bf(x0.z); a0[3]=(short)f2bf(x0.w);
        a0[4]=(short)f2bf(x1.x); a0[5]=(short)f2bf(x1.y); a0[6]=(short)f2bf(x1.z); a0[7]=(short)f2bf(x1.w);
    }
    floatx4 z4 = {0.f,0.f,0.f,0.f};
    #pragma unroll
    for (int nt = 0; nt < 4; ++nt) {
        int n = nt*16 + l16;
        short8 b0 = *(const short8*)(W3T + (size_t)n*32 + quad*8);
        floatx4 d = __builtin_amdgcn_mfma_f32_16x16x32_bf16(a0, b0, z4, 0, 0, 0);
        #pragma unroll
        for (int rp = 0; rp < 2; ++rp) {
            int e = e0 + quad*4 + 2*rp;
            unsigned pack = (unsigned)f2bf(d[2*rp]) | ((unsigned)f2bf(d[2*rp+1]) << 16);
            *(unsigned*)(Cp + (size_t)(e >> 1)*128 + n*2) = pack;
        }
    }
}

// Embed via MFMA + fused iter-0 [A|B]. Tiles over SLOTS (degree-sorted perm).
__global__ __launch_bounds__(256) void embed_fused_kernel(
        const float* __restrict__ node_data, const unsigned short* __restrict__ WeT,
        const float* __restrict__ b_embed, const int* __restrict__ perm,
        unsigned short* __restrict__ hb,
        const unsigned short* __restrict__ WabT, const float* __restrict__ b_msg,
        unsigned short* __restrict__ Ab, unsigned short* __restrict__ Bb, int n_nodes) {
    __shared__ unsigned short hs[16 * 68];
    int jt = threadIdx.x >> 6, lane = threadIdx.x & 63;
    int m0 = blockIdx.x * 16;
    if (m0 >= n_nodes) return;
    int quad = lane >> 4, l16 = lane & 15;
    int slot_l = m0 + l16; if (slot_l >= n_nodes) slot_l = n_nodes - 1;
    int real_l = perm[slot_l];
    short8 a0 = {0,0,0,0,0,0,0,0};
    if (quad < 2) {
        const float4* np = (const float4*)(node_data + (size_t)real_l*VD + quad*8);
        float4 x0 = np[0], x1 = np[1];
        a0[0]=(short)f2bf(x0.x); a0[1]=(short)f2bf(x0.y); a0[2]=(short)f2bf(x0.z); a0[3]=(short)f2bf(x0.w);
        a0[4]=(short)f2bf(x1.x); a0[5]=(short)f2bf(x1.y); a0[6]=(short)f2bf(x1.z); a0[7]=(short)f2bf(x1.w);
    }
    int j = jt*16 + l16;
    short8 b0 = *(const short8*)(WeT + (size_t)j*32 + quad*8);
    floatx4 z4 = {0.f,0.f,0.f,0.f};
    floatx4 d = __builtin_amdgcn_mfma_f32_16x16x32_bf16(a0, b0, z4, 0, 0, 0);
    float bias = b_embed[j];
    #pragma unroll
    for (int r = 0; r < 4; ++r) {
        int slot = m0 + quad*4 + r;
        unsigned short v16 = f2bf(d[r] + bias);
        hs[(quad*4 + r)*68 + j] = v16;
        if (slot < n_nodes) hb[(size_t)slot*SD + j] = v16;   // slot-indexed
    }
    __syncthreads();
    short8 aa0 = *(const short8*)(hs + l16*68 + quad*8);
    short8 aa1 = *(const short8*)(hs + l16*68 + 32 + quad*8);
    #pragma unroll
    for (int s = 0; s < 2; ++s) {
        int ncol = (jt + 4*s)*16 + l16;
        const short8* bp = (const short8*)(WabT + (size_t)ncol*SD + quad*8);
        floatx4 dd = __builtin_amdgcn_mfma_f32_16x16x32_bf16(aa0, bp[0], z4, 0, 0, 0);
        dd = __builtin_amdgcn_mfma_f32_16x16x32_bf16(aa1, bp[4], dd, 0, 0, 0);
        float bias2 = (s == 0) ? b_msg[ncol] : 0.f;
        int jc = jt*16 + l16;
        #pragma unroll
        for (int r = 0; r < 4; ++r) {
            int slot = m0 + quad*4 + r;
            if (slot >= n_nodes) break;
            float v = dd[r] + bias2;
            if (s == 0) Ab[(size_t)slot*SD + jc] = f2bf(v);          // slot-indexed
            else        Bb[(size_t)perm[slot]*SD + jc] = f2bf(v);    // node-indexed
        }
    }
}

// One full MPNN iteration. Block = 16-SLOT tile (degree-sorted), 4 waves.
template<int FIRST, int LAST>
__global__ __launch_bounds__(256) void mpnn_iter_kernel(
        const unsigned short* __restrict__ hbr, unsigned short* __restrict__ hbw,
        const unsigned short* __restrict__ Abr, const unsigned short* __restrict__ Bbr,
        unsigned short* __restrict__ Abw, unsigned short* __restrict__ Bbw,
        const unsigned short* __restrict__ Cp, const int* __restrict__ src_csr,
        const int* __restrict__ row_ptr, const int* __restrict__ deg,
        const int* __restrict__ perm,
        unsigned short* __restrict__ m_accb,
        const unsigned short* __restrict__ WiT, const unsigned short* __restrict__ WhT,
        const float* __restrict__ b_i, const float* __restrict__ b_h,
        const unsigned short* __restrict__ WabT, const float* __restrict__ b_msg,
        const float* __restrict__ W_r1, const float* __restrict__ b_r1,
        const float* __restrict__ W_r2, float* __restrict__ partials,
        int n_nodes) {
    __shared__ unsigned short hsm[16 * 68];   // m tile (bf16)
    __shared__ unsigned short hsn[16 * 68];   // hnew tile (bf16)
    int w = threadIdx.x >> 6, lane = threadIdx.x & 63;
    int m0 = blockIdx.x * 16;
    if (m0 >= n_nodes) return;

    // ---- Phase 1: aggregation, 4 slots per wave (near-equal degrees) ----
    int e0[4], dg[4], pend[4]; float aval[4], base[4];
    #pragma unroll
    for (int u = 0; u < 4; ++u) {
        int slot = m0 + w*4 + u;
        bool v = slot < n_nodes;
        int sc = v ? slot : n_nodes - 1;
        int real = perm[sc];
        e0[u] = row_ptr[real];
        dg[u] = v ? deg[real] : 0;
        int pairs = (dg[u] + 1) >> 1;
        pend[u] = (e0[u] >> 1) + (pairs > 0 ? pairs - 1 : 0);
        aval[u] = bf2f(Abr[(size_t)sc*SD + lane]);
        base[u] = FIRST ? 0.f : bf2f(m_accb[(size_t)sc*SD + lane]);
    }
    float acc[4] = {0.f, 0.f, 0.f, 0.f};
    int mx = max(max(dg[0], dg[1]), max(dg[2], dg[3]));
    for (int c = 0; c*16 < mx; ++c) {
        #pragma unroll
        for (int up = 0; up < 2; ++up) {
            int sv[2]; unsigned cp2[2][8]; float bv[2][16];
            #pragma unroll
            for (int q = 0; q < 2; ++q) {
                int u = up*2 + q;
                int ilast = e0[u] + (dg[u] > 0 ? dg[u] - 1 : 0);
                int i = e0[u] + c*16 + (lane & 15);
                if (i > ilast) i = ilast;
                sv[q] = src_csr[i];
                int pb = (e0[u] >> 1) + c*8;
                #pragma unroll
                for (int t2 = 0; t2 < 8; ++t2) {
                    int pi = pb + t2; if (pi > pend[u]) pi = pend[u];
                    cp2[q][t2] = *(const unsigned*)(Cp + (size_t)pi*128 + lane*2);
                }
            }
            #pragma unroll
            for (int q = 0; q < 2; ++q) {
                #pragma unroll
                for (int t = 0; t < 16; ++t) {
                    int s = __builtin_amdgcn_readlane(sv[q], t);
                    bv[q][t] = bf2f(Bbr[(size_t)s*SD + lane]);
                }
            }
            #pragma unroll
            for (int q = 0; q < 2; ++q) {
                int u = up*2 + q;
                int cnt = dg[u] - c*16;
                #pragma unroll
                for (int t = 0; t < 16; ++t) {
                    if (t < cnt) {
                        float cv = bf2f((unsigned short)((t & 1) ? (cp2[q][t>>1] >> 16)
                                                                 : (cp2[q][t>>1] & 0xFFFF)));
                        acc[u] += fmaxf(aval[u] + bv[q][t] + cv, 0.f);
                    }
                }
            }
        }
    }
    #pragma unroll
    for (int u = 0; u < 4; ++u) {
        int slot = m0 + w*4 + u;
        unsigned short nv16 = f2bf(base[u] + acc[u]);
        hsm[(w*4 + u)*68 + lane] = nv16;
        if (!LAST && slot < n_nodes) m_accb[(size_t)slot*SD + lane] = nv16;
    }
    __syncthreads();

    // ---- Phase 2: GRU via MFMA (slot-indexed hb: coalesced) ----
    int quad = lane >> 4, l16 = lane & 15;
    int srow = m0 + l16; if (srow >= n_nodes) srow = n_nodes - 1;
    const short8* hp = (const short8*)(hbr + (size_t)srow*SD + quad*8);
    short8 ha0 = hp[0], ha1 = hp[4];
    short8 ma0 = *(const short8*)(hsm + l16*68 + quad*8);
    short8 ma1 = *(const short8*)(hsm + l16*68 + 32 + quad*8);
    int j0 = w * 16;
    floatx4 di[3], dh[3];
    floatx4 z4 = {0.f,0.f,0.f,0.f};
    #pragma unroll
    for (int g = 0; g < 3; ++g) {
        int n = g*64 + j0 + l16;
        const short8* bi = (const short8*)(WiT + (size_t)n*SD + quad*8);
        const short8* bh = (const short8*)(WhT + (size_t)n*SD + quad*8);
        di[g] = __builtin_amdgcn_mfma_f32_16x16x32_bf16(ma0, bi[0], z4,    0, 0, 0);
        di[g] = __builtin_amdgcn_mfma_f32_16x16x32_bf16(ma1, bi[4], di[g], 0, 0, 0);
        dh[g] = __builtin_amdgcn_mfma_f32_16x16x32_bf16(ha0, bh[0], z4,    0, 0, 0);
        dh[g] = __builtin_amdgcn_mfma_f32_16x16x32_bf16(ha1, bh[4], dh[g], 0, 0, 0);
    }
    int j = j0 + l16;
    float bir = b_i[j], biz = b_i[64+j], bin = b_i[128+j];
    float bhr = b_h[j], bhz = b_h[64+j], bhn = b_h[128+j];
    #pragma unroll
    for (int r = 0; r < 4; ++r) {
        int slot = m0 + quad*4 + r;
        int sc = slot < n_nodes ? slot : n_nodes - 1;
        float rg = sigmoid_f(di[0][r] + bir + dh[0][r] + bhr);
        float zg = sigmoid_f(di[1][r] + biz + dh[1][r] + bhz);
        float ng = tanh_f(di[2][r] + bin + rg * (dh[2][r] + bhn));
        float hold = bf2f(hbr[(size_t)sc*SD + j]);
        float hnew = (1.f - zg) * ng + zg * hold;
        unsigned short hb16 = f2bf(hnew);
        hsn[(quad*4 + r)*68 + j] = hb16;
        if (!LAST && slot < n_nodes) hbw[(size_t)slot*SD + j] = hb16;
    }

    if (!LAST) {
        // ---- Phase 3a: next iteration's [A|B] ----
        __syncthreads();
        short8 a0 = *(const short8*)(hsn + l16*68 + quad*8);
        short8 a1 = *(const short8*)(hsn + l16*68 + 32 + quad*8);
        #pragma unroll
        for (int s = 0; s < 2; ++s) {
            int ncol = (w + 4*s)*16 + l16;
            const short8* bp = (const short8*)(WabT + (size_t)ncol*SD + quad*8);
            floatx4 d = __builtin_amdgcn_mfma_f32_16x16x32_bf16(a0, bp[0], z4, 0, 0, 0);
            d = __builtin_amdgcn_mfma_f32_16x16x32_bf16(a1, bp[4], d, 0, 0, 0);
            float bias = (s == 0) ? b_msg[ncol] : 0.f;
            int jc = w*16 + l16;
            #pragma unroll
            for (int r = 0; r < 4; ++r) {
                int slot = m0 + quad*4 + r;
                if (slot >= n_nodes) break;
                float v = d[r] + bias;
                if (s == 0) Abw[(size_t)slot*SD + jc] = f2bf(v);        // slot-indexed
                else        Bbw[(size_t)perm[slot]*SD + jc] = f2bf(v);  // node-indexed
            }
        }
    } else {
        // ---- Phase 3b: fused readout partials ----
        __syncthreads();
        __shared__ float ts[16 * 12];
        __shared__ float po[512];
        int tid = threadIdx.x;
        if (tid < 16 * RH) {
            int node = tid / RH, i = tid - node * RH;
            float a = b_r1[i];
            #pragma unroll 8
            for (int k = 0; k < SD; ++k)
                a += bf2f(hsn[node*68 + k]) * W_r1[k*RH + i];
            ts[node*12 + i] = fmaxf(a, 0.f);
        }
        __syncthreads();
        #pragma unroll
        for (int s = 0; s < 2; ++s) {
            int task = tid + s*256;
            int node = task >> 5, c = task & 31;
            float v = 0.f;
            if (m0 + node < n_nodes) {
                #pragma unroll
                for (int i = 0; i < RH; ++i) v += ts[node*12 + i] * W_r2[i*RD + c];
            }
            po[task] = v;
        }
        __syncthreads();
        if (tid < RD) {
            float s2 = 0.f;
            #pragma unroll
            for (int n = 0; n < 16; ++n) s2 += po[n*32 + tid];
            partials[(size_t)blockIdx.x * RD + tid] = s2;
        }
    }
}

// Final: out[c] = sum over blocks of partials + n_nodes * b_r2[c]. One block.
__global__ __launch_bounds__(1024) void final_sum_kernel(
        const float* __restrict__ partials, const float* __restrict__ b_r2,
        float* __restrict__ out, int mtiles, int n_nodes) {
    __shared__ float red[1024];
    int c = threadIdx.x & 31, g = threadIdx.x >> 5;
    float s = 0.f;
    for (int t = g; t < mtiles; t += 32) s += partials[(size_t)t*RD + c];
    red[threadIdx.x] = s;
    __syncthreads();
    #pragma unroll
    for (int off = 512; off >= 32; off >>= 1) {
        if ((int)threadIdx.x < off) red[threadIdx.x] += red[threadIdx.x + off];
        __syncthreads();
    }
    if (threadIdx.x < RD) out[threadIdx.x] = red[threadIdx.x] + (float)n_nodes * b_r2[threadIdx.x];
}

extern "C" void kernel_launch(void* const* d_in, const int* in_sizes, int n_in,
                              void* d_out, int out_size, void* d_ws, size_t ws_size,
                              hipStream_t stream) {
    const float* node_data = (const float*)d_in[0];
    const float* edge_data = (const float*)d_in[1];
    const int*   edge_src  = (const int*)d_in[2];
    const int*   edge_dst  = (const int*)d_in[3];
    const float* W_embed   = (const float*)d_in[4];
    const float* b_embed   = (const float*)d_in[5];
    const float* W_msg     = (const float*)d_in[6];
    const float* b_msg     = (const float*)d_in[7];
    const float* W_i       = (const float*)d_in[8];
    const float* b_i       = (const float*)d_in[9];
    const float* W_h       = (const float*)d_in[10];
    const float* b_h       = (const float*)d_in[11];
    const float* W_r1      = (const float*)d_in[12];
    const float* b_r1      = (const float*)d_in[13];
    const float* W_r2      = (const float*)d_in[14];
    const float* b_r2      = (const float*)d_in[15];

    int n_nodes = in_sizes[0] / VD;    // 20000
    int n_edges = in_sizes[2];         // 320000
    int Lmax = n_edges + n_nodes + 64; // padded CSR capacity
    int mtiles = (n_nodes + 15) / 16;

    char* ws = (char*)d_ws;
    size_t off = 0;
    auto alloc = [&](size_t bytes) {
        void* p = ws + off;
        off = (off + bytes + 255) & ~(size_t)255;
        return p;
    };
    unsigned short* m_accb = (unsigned short*)alloc((size_t)n_nodes * SD * 2);
    unsigned short* hbA = (unsigned short*)alloc((size_t)n_nodes * SD * 2);
    unsigned short* hbB = (unsigned short*)alloc((size_t)n_nodes * SD * 2);
    unsigned short* Ab0 = (unsigned short*)alloc((size_t)n_nodes * SD * 2);
    unsigned short* Bb0 = (unsigned short*)alloc((size_t)n_nodes * SD * 2);
    unsigned short* Ab1 = (unsigned short*)alloc((size_t)n_nodes * SD * 2);
    unsigned short* Bb1 = (unsigned short*)alloc((size_t)n_nodes * SD * 2);
    unsigned short* Cp  = (unsigned short*)alloc((size_t)(Lmax + 32) * SD * 2);
    int*   src_csr      = (int*)alloc((size_t)(Lmax + 32) * sizeof(int));
    int*   row_ptr      = (int*)alloc((size_t)(n_nodes + 1) * sizeof(int));
    int*   perm         = (int*)alloc((size_t)n_nodes * sizeof(int));
    float* partials     = (float*)alloc((size_t)mtiles * RD * sizeof(float));
    // contiguous zero-init region: deg, fillc, eid (one memset)
    char*  zbase        = (char*)alloc(0);
    int*   deg          = (int*)alloc((size_t)n_nodes * sizeof(int));
    int*   fillc        = (int*)alloc((size_t)n_nodes * sizeof(int));
    int*   eid          = (int*)alloc((size_t)(Lmax + 32) * sizeof(int));
    char*  zend         = (char*)alloc(0);
    unsigned short* WabT = (unsigned short*)alloc(128*64*2);
    unsigned short* WiT  = (unsigned short*)alloc(192*64*2);
    unsigned short* WhT  = (unsigned short*)alloc(192*64*2);
    unsigned short* W3T  = (unsigned short*)alloc(64*32*2);
    unsigned short* WeT  = (unsigned short*)alloc(64*32*2);
    (void)ws_size; (void)n_in;

    hipMemsetAsync(zbase, 0, (size_t)(zend - zbase), stream);

    prep_hist_kernel<<<(PREP_N + n_edges + 255)/256, 256, 0, stream>>>(
        W_msg, W_i, W_h, W_embed, WabT, WiT, WhT, W3T, WeT, edge_dst, deg, n_edges);

    scan_kernel<<<1, 1024, 0, stream>>>(deg, row_ptr, perm, n_nodes);

    fill_kernel<<<(n_edges + 255)/256, 256, 0, stream>>>(edge_dst, row_ptr, fillc, eid, n_edges);

    int ec_waves = (Lmax + 15) / 16;
    edgeconst_kernel<<<(ec_waves + 3)/4, 256, 0, stream>>>(eid, edge_src, edge_data, W3T,
                                                           src_csr, Cp, Lmax);

    embed_fused_kernel<<<mtiles, 256, 0, stream>>>(node_data, WeT, b_embed, perm, hbA,
                                                   WabT, b_msg, Ab0, Bb0, n_nodes);

    // it0: read Ab0/Bb0, hbA -> hbB, write Ab1/Bb1
    mpnn_iter_kernel<1,0><<<mtiles, 256, 0, stream>>>(hbA, hbB, Ab0, Bb0, Ab1, Bb1,
        Cp, src_csr, row_ptr, deg, perm, m_accb, WiT, WhT, b_i, b_h, WabT, b_msg,
        W_r1, b_r1, W_r2, partials, n_nodes);
    // it1: read Ab1/Bb1, hbB -> hbA, write Ab0/Bb0
    mpnn_iter_kernel<0,0><<<mtiles, 256, 0, stream>>>(hbB, hbA, Ab1, Bb1, Ab0, Bb0,
        Cp, src_csr, row_ptr, deg, perm, m_accb, WiT, WhT, b_i, b_h, WabT, b_msg,
        W_r1, b_r1, W_r2, partials, n_nodes);
    // it2 (LAST): fused readout partials
    mpnn_iter_kernel<0,1><<<mtiles, 256, 0, stream>>>(hbA, hbB, Ab0, Bb0, Ab1, Bb1,
        Cp, src_csr, row_ptr, deg, perm, m_accb, WiT, WhT, b_i, b_h, WabT, b_msg,
        W_r1, b_r1, W_r2, partials, n_nodes);

    final_sum_kernel<<<1, 1024, 0, stream>>>(partials, b_r2, (float*)d_out, mtiles, n_nodes);
}

// Round 11
// 299.893 us; speedup vs baseline: 1.1328x; 1.0081x over previous
//
#include <hip/hip_runtime.h>

static constexpr int VD = 16;     // vertex feature dim
static constexpr int SD = 64;     // state dim
static constexpr int ED = 16;     // edge feature dim
static constexpr int RH = 10, RD = 32;
static constexpr int N_ITERS = 3;
static constexpr int PREP_N = 128*64 + 192*64 + 64*32 + 64*32;  // 24576

typedef __attribute__((ext_vector_type(8))) short short8;
typedef __attribute__((ext_vector_type(4))) float floatx4;

__device__ __forceinline__ float sigmoid_f(float x) {
    return 1.f / (1.f + __expf(-x));
}
__device__ __forceinline__ float tanh_f(float x) {
    x = fminf(fmaxf(x, -20.f), 20.f);
    float e = __expf(2.f * x);
    return (e - 1.f) / (e + 1.f);
}
__device__ __forceinline__ unsigned short f2bf(float x) {   // round-to-nearest-even
    unsigned u = __float_as_uint(x);
    unsigned r = (u + 0x7FFFu + ((u >> 16) & 1u)) >> 16;
    return (unsigned short)r;
}
__device__ __forceinline__ float bf2f(unsigned short s) {
    return __uint_as_float(((unsigned)s) << 16);
}

// Merged: one-time weight transposes (first PREP_N ids) + degree histogram (rest).
__global__ void prep_hist_kernel(const float* __restrict__ W_msg,
                                 const float* __restrict__ W_i, const float* __restrict__ W_h,
                                 const float* __restrict__ W_embed,
                                 unsigned short* __restrict__ WabT, unsigned short* __restrict__ WiT,
                                 unsigned short* __restrict__ WhT, unsigned short* __restrict__ W3T,
                                 unsigned short* __restrict__ WeT,
                                 const int* __restrict__ edge_dst, int* __restrict__ deg,
                                 int n_edges) {
    int gid = blockIdx.x * blockDim.x + threadIdx.x;
    int i = gid;
    if (i < 128*64) {                       // WabT[n][k]
        int n = i >> 6, k = i & 63;
        WabT[i] = f2bf(W_msg[((n < 64 ? 0 : 64) + k)*64 + (n & 63)]);
    }
    int j = i - 128*64;
    if (j >= 0 && j < 192*64) {             // WiT/WhT[n][k] = W[k][n]
        int n = j >> 6, k = j & 63;
        WiT[j] = f2bf(W_i[k*192 + n]);
        WhT[j] = f2bf(W_h[k*192 + n]);
    }
    int l = i - 128*64 - 192*64;
    if (l >= 0 && l < 64*32) {              // W3T[n][k], k padded 16->32
        int n = l >> 5, k = l & 31;
        W3T[l] = (k < 16) ? f2bf(W_msg[(128+k)*64 + n]) : (unsigned short)0;
    }
    int m = i - 128*64 - 192*64 - 64*32;
    if (m >= 0 && m < 64*32) {              // WeT[n][k], k padded 16->32
        int n = m >> 5, k = m & 31;
        WeT[m] = (k < 16) ? f2bf(W_embed[k*64 + n]) : (unsigned short)0;
    }
    int e = gid - PREP_N;
    if (e >= 0 && e < n_edges) atomicAdd(&deg[edge_dst[e]], 1);
}

// Single block: scan of EVEN-PADDED degrees -> row_ptr; degree-bucket counting sort
// (descending) -> perm, all with LDS atomics.
__global__ __launch_bounds__(1024) void scan_kernel(const int* __restrict__ deg,
                                                    int* __restrict__ row_ptr,
                                                    int* __restrict__ perm,
                                                    int n_nodes) {
    __shared__ int wsum[16];
    __shared__ int bh[128];
    __shared__ int bbase[128];
    int lid = threadIdx.x, lane = lid & 63, wv = lid >> 6;
    if (lid < 128) bh[lid] = 0;
    __syncthreads();
    int C = (n_nodes + 1023) >> 10;
    int start = lid * C;
    int lsum = 0;
    for (int i = 0; i < C; ++i) {
        int idx = start + i;
        if (idx < n_nodes) {
            int d = deg[idx];
            lsum += (d + 1) & ~1;
            atomicAdd(&bh[d < 127 ? d : 127], 1);
        }
    }
    int x = lsum;
    #pragma unroll
    for (int off = 1; off < 64; off <<= 1) {
        int y = __shfl_up(x, off);
        if (lane >= off) x += y;
    }
    if (lane == 63) wsum[wv] = x;
    __syncthreads();
    if (lid == 0) {
        int run = 0;
        for (int b = 127; b >= 0; --b) { bbase[b] = run; run += bh[b]; }
    }
    if (wv == 0 && lane < 16) {
        int t = wsum[lane];
        #pragma unroll
        for (int off = 1; off < 16; off <<= 1) {
            int y = __shfl_up(t, off);
            if (lane >= off) t += y;
        }
        wsum[lane] = t;
    }
    __syncthreads();
    int wbase = (wv > 0) ? wsum[wv - 1] : 0;
    int run = wbase + x - lsum;
    for (int i = 0; i < C; ++i) {
        int idx = start + i;
        if (idx < n_nodes) {
            int d = deg[idx];
            row_ptr[idx] = run; run += (d + 1) & ~1;
            int b = d < 127 ? d : 127;
            int pos = atomicAdd(&bbase[b], 1);
            perm[pos] = idx;
        }
    }
}

// Merged dispatch: blocks [0, fill_blocks) do CSR fill; the rest do embed+iter0-AB.
__global__ __launch_bounds__(256) void fill_embed_kernel(
        const int* __restrict__ edge_dst, const int* __restrict__ row_ptr,
        int* __restrict__ fillc, int* __restrict__ eid, int n_edges,
        const float* __restrict__ node_data, const unsigned short* __restrict__ WeT,
        const float* __restrict__ b_embed, const int* __restrict__ perm,
        unsigned short* __restrict__ hb,
        const unsigned short* __restrict__ WabT, const float* __restrict__ b_msg,
        unsigned short* __restrict__ Ab, unsigned short* __restrict__ Bb,
        int n_nodes, int fill_blocks) {
    if ((int)blockIdx.x < fill_blocks) {
        int e = blockIdx.x * 256 + threadIdx.x;
        if (e < n_edges) {
            int d = edge_dst[e];
            int ofs = atomicAdd(&fillc[d], 1);
            eid[row_ptr[d] + ofs] = e;
        }
        return;
    }
    __shared__ unsigned short hs[16 * 68];
    int jt = threadIdx.x >> 6, lane = threadIdx.x & 63;
    int m0 = ((int)blockIdx.x - fill_blocks) * 16;
    if (m0 >= n_nodes) return;
    int quad = lane >> 4, l16 = lane & 15;
    int slot_l = m0 + l16; if (slot_l >= n_nodes) slot_l = n_nodes - 1;
    int real_l = perm[slot_l];
    short8 a0 = {0,0,0,0,0,0,0,0};
    if (quad < 2) {
        const float4* np = (const float4*)(node_data + (size_t)real_l*VD + quad*8);
        float4 x0 = np[0], x1 = np[1];
        a0[0]=(short)f2bf(x0.x); a0[1]=(short)f2bf(x0.y); a0[2]=(short)f2bf(x0.z); a0[3]=(short)f2bf(x0.w);
        a0[4]=(short)f2bf(x1.x); a0[5]=(short)f2bf(x1.y); a0[6]=(short)f2bf(x1.z); a0[7]=(short)f2bf(x1.w);
    }
    int j = jt*16 + l16;
    short8 b0 = *(const short8*)(WeT + (size_t)j*32 + quad*8);
    floatx4 z4 = {0.f,0.f,0.f,0.f};
    floatx4 d = __builtin_amdgcn_mfma_f32_16x16x32_bf16(a0, b0, z4, 0, 0, 0);
    float bias = b_embed[j];
    #pragma unroll
    for (int r = 0; r < 4; ++r) {
        int slot = m0 + quad*4 + r;
        unsigned short v16 = f2bf(d[r] + bias);
        hs[(quad*4 + r)*68 + j] = v16;
        if (slot < n_nodes) hb[(size_t)slot*SD + j] = v16;   // slot-indexed
    }
    __syncthreads();
    short8 aa0 = *(const short8*)(hs + l16*68 + quad*8);
    short8 aa1 = *(const short8*)(hs + l16*68 + 32 + quad*8);
    #pragma unroll
    for (int s = 0; s < 2; ++s) {
        int ncol = (jt + 4*s)*16 + l16;
        const short8* bp = (const short8*)(WabT + (size_t)ncol*SD + quad*8);
        floatx4 dd = __builtin_amdgcn_mfma_f32_16x16x32_bf16(aa0, bp[0], z4, 0, 0, 0);
        dd = __builtin_amdgcn_mfma_f32_16x16x32_bf16(aa1, bp[4], dd, 0, 0, 0);
        float bias2 = (s == 0) ? b_msg[ncol] : 0.f;
        int jc = jt*16 + l16;
        #pragma unroll
        for (int r = 0; r < 4; ++r) {
            int slot = m0 + quad*4 + r;
            if (slot >= n_nodes) break;
            float v = dd[r] + bias2;
            if (s == 0) Ab[(size_t)slot*SD + jc] = f2bf(v);          // slot-indexed
            else        Bb[(size_t)perm[slot]*SD + jc] = f2bf(v);    // node-indexed
        }
    }
}

// Once: Cp[pair][col] (uint: lo=even edge, hi=odd) = edge_data@W3 (bf16) + src_csr gather.
__global__ __launch_bounds__(256) void edgeconst_kernel(
        const int* __restrict__ eid, const int* __restrict__ edge_src,
        const float* __restrict__ edge_data, const unsigned short* __restrict__ W3T,
        int* __restrict__ src_csr, unsigned short* __restrict__ Cp, int Lmax) {
    int w = blockIdx.x * 4 + (threadIdx.x >> 6);
    int lane = threadIdx.x & 63;
    int e0 = w * 16;
    if (e0 >= Lmax) return;
    int quad = lane >> 4, l16 = lane & 15;
    int erow = e0 + l16;
    int ev = eid[erow];                      // coalesced; 0 for pads
    if (quad == 0) src_csr[erow] = edge_src[ev];
    short8 a0 = {0,0,0,0,0,0,0,0};
    if (quad < 2) {
        const float4* ep = (const float4*)(edge_data + (size_t)ev*ED + quad*8);
        float4 x0 = ep[0], x1 = ep[1];
        a0[0]=(short)f2bf(x0.x); a0[1]=(short)f2bf(x0.y); a0[2]=(short)f2bf(x0.z); a0[3]=(short)f2bf(x0.w);
        a0[4]=(short)f2bf(x1.x); a0[5]=(short)f2bf(x1.y); a0[6]=(short)f2bf(x1.z); a0[7]=(short)f2bf(x1.w);
    }
    floatx4 z4 = {0.f,0.f,0.f,0.f};
    #pragma unroll
    for (int nt = 0; nt < 4; ++nt) {
        int n = nt*16 + l16;
        short8 b0 = *(const short8*)(W3T + (size_t)n*32 + quad*8);
        floatx4 d = __builtin_amdgcn_mfma_f32_16x16x32_bf16(a0, b0, z4, 0, 0, 0);
        #pragma unroll
        for (int rp = 0; rp < 2; ++rp) {
            int e = e0 + quad*4 + 2*rp;
            unsigned pack = (unsigned)f2bf(d[2*rp]) | ((unsigned)f2bf(d[2*rp+1]) << 16);
            *(unsigned*)(Cp + (size_t)(e >> 1)*128 + n*2) = pack;
        }
    }
}

// One full MPNN iteration. Block = 16-SLOT tile (degree-sorted), 4 waves.
// Agg: per-node 64-edge src window preloaded in ONE wave-wide load (kills the
// per-chunk src_csr latency head); Cp loads overlap the Bb gathers.
template<int FIRST, int LAST>
__global__ __launch_bounds__(256) void mpnn_iter_kernel(
        const unsigned short* __restrict__ hbr, unsigned short* __restrict__ hbw,
        const unsigned short* __restrict__ Abr, const unsigned short* __restrict__ Bbr,
        unsigned short* __restrict__ Abw, unsigned short* __restrict__ Bbw,
        const unsigned short* __restrict__ Cp, const int* __restrict__ src_csr,
        const int* __restrict__ row_ptr, const int* __restrict__ deg,
        const int* __restrict__ perm,
        unsigned short* __restrict__ m_accb,
        const unsigned short* __restrict__ WiT, const unsigned short* __restrict__ WhT,
        const float* __restrict__ b_i, const float* __restrict__ b_h,
        const unsigned short* __restrict__ WabT, const float* __restrict__ b_msg,
        const float* __restrict__ W_r1, const float* __restrict__ b_r1,
        const float* __restrict__ W_r2, float* __restrict__ partials,
        int n_nodes) {
    __shared__ unsigned short hsm[16 * 68];   // m tile (bf16)
    __shared__ unsigned short hsn[16 * 68];   // hnew tile (bf16)
    int w = threadIdx.x >> 6, lane = threadIdx.x & 63;
    int m0 = blockIdx.x * 16;
    if (m0 >= n_nodes) return;

    // ---- Phase 1: aggregation, 4 slots per wave (near-equal degrees) ----
    int e0[4], dg[4], pend[4], sve[4]; float aval[4], base[4];
    #pragma unroll
    for (int u = 0; u < 4; ++u) {
        int slot = m0 + w*4 + u;
        bool v = slot < n_nodes;
        int sc = v ? slot : n_nodes - 1;
        int real = perm[sc];
        e0[u] = row_ptr[real];
        dg[u] = v ? deg[real] : 0;
        int pairs = (dg[u] + 1) >> 1;
        pend[u] = (e0[u] >> 1) + (pairs > 0 ? pairs - 1 : 0);
        int ilast = e0[u] + (dg[u] > 0 ? dg[u] - 1 : 0);
        int iw = e0[u] + lane; if (iw > ilast) iw = ilast;
        sve[u] = src_csr[iw];                 // 64-edge window, ONE load per node
        aval[u] = bf2f(Abr[(size_t)sc*SD + lane]);
        base[u] = FIRST ? 0.f : bf2f(m_accb[(size_t)sc*SD + lane]);
    }
    float acc[4] = {0.f, 0.f, 0.f, 0.f};
    int mx = max(max(dg[0], dg[1]), max(dg[2], dg[3]));
    for (int c = 0; c*16 < mx; ++c) {
        if (c > 0 && (c & 3) == 0) {          // refresh window (deg > 64: ~never)
            #pragma unroll
            for (int u = 0; u < 4; ++u) {
                int ilast = e0[u] + (dg[u] > 0 ? dg[u] - 1 : 0);
                int iw = e0[u] + c*16 + lane; if (iw > ilast) iw = ilast;
                sve[u] = src_csr[iw];
            }
        }
        int cb = (c & 3) * 16;
        #pragma unroll
        for (int up = 0; up < 2; ++up) {
            unsigned cp2[2][8]; float bv[2][16];
            #pragma unroll
            for (int q = 0; q < 2; ++q) {
                int u = up*2 + q;
                int pb = (e0[u] >> 1) + c*8;
                #pragma unroll
                for (int t2 = 0; t2 < 8; ++t2) {
                    int pi = pb + t2; if (pi > pend[u]) pi = pend[u];
                    cp2[q][t2] = *(const unsigned*)(Cp + (size_t)pi*128 + lane*2);
                }
            }
            #pragma unroll
            for (int q = 0; q < 2; ++q) {
                int u = up*2 + q;
                #pragma unroll
                for (int t = 0; t < 16; ++t) {
                    int s = __builtin_amdgcn_readlane(sve[u], cb + t);  // no load wait
                    bv[q][t] = bf2f(Bbr[(size_t)s*SD + lane]);
                }
            }
            #pragma unroll
            for (int q = 0; q < 2; ++q) {
                int u = up*2 + q;
                int cnt = dg[u] - c*16;
                #pragma unroll
                for (int t = 0; t < 16; ++t) {
                    if (t < cnt) {
                        float cv = bf2f((unsigned short)((t & 1) ? (cp2[q][t>>1] >> 16)
                                                                 : (cp2[q][t>>1] & 0xFFFF)));
                        acc[u] += fmaxf(aval[u] + bv[q][t] + cv, 0.f);
                    }
                }
            }
        }
    }
    #pragma unroll
    for (int u = 0; u < 4; ++u) {
        int slot = m0 + w*4 + u;
        unsigned short nv16 = f2bf(base[u] + acc[u]);
        hsm[(w*4 + u)*68 + lane] = nv16;
        if (!LAST && slot < n_nodes) m_accb[(size_t)slot*SD + lane] = nv16;
    }
    __syncthreads();

    // ---- Phase 2: GRU via MFMA (slot-indexed hb: coalesced) ----
    int quad = lane >> 4, l16 = lane & 15;
    int srow = m0 + l16; if (srow >= n_nodes) srow = n_nodes - 1;
    const short8* hp = (const short8*)(hbr + (size_t)srow*SD + quad*8);
    short8 ha0 = hp[0], ha1 = hp[4];
    short8 ma0 = *(const short8*)(hsm + l16*68 + quad*8);
    short8 ma1 = *(const short8*)(hsm + l16*68 + 32 + quad*8);
    int j0 = w * 16;
    floatx4 di[3], dh[3];
    floatx4 z4 = {0.f,0.f,0.f,0.f};
    #pragma unroll
    for (int g = 0; g < 3; ++g) {
        int n = g*64 + j0 + l16;
        const short8* bi = (const short8*)(WiT + (size_t)n*SD + quad*8);
        const short8* bh = (const short8*)(WhT + (size_t)n*SD + quad*8);
        di[g] = __builtin_amdgcn_mfma_f32_16x16x32_bf16(ma0, bi[0], z4,    0, 0, 0);
        di[g] = __builtin_amdgcn_mfma_f32_16x16x32_bf16(ma1, bi[4], di[g], 0, 0, 0);
        dh[g] = __builtin_amdgcn_mfma_f32_16x16x32_bf16(ha0, bh[0], z4,    0, 0, 0);
        dh[g] = __builtin_amdgcn_mfma_f32_16x16x32_bf16(ha1, bh[4], dh[g], 0, 0, 0);
    }
    int j = j0 + l16;
    float bir = b_i[j], biz = b_i[64+j], bin = b_i[128+j];
    float bhr = b_h[j], bhz = b_h[64+j], bhn = b_h[128+j];
    #pragma unroll
    for (int r = 0; r < 4; ++r) {
        int slot = m0 + quad*4 + r;
        int sc = slot < n_nodes ? slot : n_nodes - 1;
        float rg = sigmoid_f(di[0][r] + bir + dh[0][r] + bhr);
        float zg = sigmoid_f(di[1][r] + biz + dh[1][r] + bhz);
        float ng = tanh_f(di[2][r] + bin + rg * (dh[2][r] + bhn));
        float hold = bf2f(hbr[(size_t)sc*SD + j]);
        float hnew = (1.f - zg) * ng + zg * hold;
        unsigned short hb16 = f2bf(hnew);
        hsn[(quad*4 + r)*68 + j] = hb16;
        if (!LAST && slot < n_nodes) hbw[(size_t)slot*SD + j] = hb16;
    }

    if (!LAST) {
        // ---- Phase 3a: next iteration's [A|B] ----
        __syncthreads();
        short8 a0 = *(const short8*)(hsn + l16*68 + quad*8);
        short8 a1 = *(const short8*)(hsn + l16*68 + 32 + quad*8);
        #pragma unroll
        for (int s = 0; s < 2; ++s) {
            int ncol = (w + 4*s)*16 + l16;
            const short8* bp = (const short8*)(WabT + (size_t)ncol*SD + quad*8);
            floatx4 d = __builtin_amdgcn_mfma_f32_16x16x32_bf16(a0, bp[0], z4, 0, 0, 0);
            d = __builtin_amdgcn_mfma_f32_16x16x32_bf16(a1, bp[4], d, 0, 0, 0);
            float bias = (s == 0) ? b_msg[ncol] : 0.f;
            int jc = w*16 + l16;
            #pragma unroll
            for (int r = 0; r < 4; ++r) {
                int slot = m0 + quad*4 + r;
                if (slot >= n_nodes) break;
                float v = d[r] + bias;
                if (s == 0) Abw[(size_t)slot*SD + jc] = f2bf(v);        // slot-indexed
                else        Bbw[(size_t)perm[slot]*SD + jc] = f2bf(v);  // node-indexed
            }
        }
    } else {
        // ---- Phase 3b: fused readout partials ----
        __syncthreads();
        __shared__ float ts[16 * 12];
        __shared__ float po[512];
        int tid = threadIdx.x;
        if (tid < 16 * RH) {
            int node = tid / RH, i = tid - node * RH;
            float a = b_r1[i];
            #pragma unroll 8
            for (int k = 0; k < SD; ++k)
                a += bf2f(hsn[node*68 + k]) * W_r1[k*RH + i];
            ts[node*12 + i] = fmaxf(a, 0.f);
        }
        __syncthreads();
        #pragma unroll
        for (int s = 0; s < 2; ++s) {
            int task = tid + s*256;
            int node = task >> 5, c = task & 31;
            float v = 0.f;
            if (m0 + node < n_nodes) {
                #pragma unroll
                for (int i = 0; i < RH; ++i) v += ts[node*12 + i] * W_r2[i*RD + c];
            }
            po[task] = v;
        }
        __syncthreads();
        if (tid < RD) {
            float s2 = 0.f;
            #pragma unroll
            for (int n = 0; n < 16; ++n) s2 += po[n*32 + tid];
            partials[(size_t)blockIdx.x * RD + tid] = s2;
        }
    }
}

// Final: out[c] = sum over blocks of partials + n_nodes * b_r2[c]. One block.
__global__ __launch_bounds__(1024) void final_sum_kernel(
        const float* __restrict__ partials, const float* __restrict__ b_r2,
        float* __restrict__ out, int mtiles, int n_nodes) {
    __shared__ float red[1024];
    int c = threadIdx.x & 31, g = threadIdx.x >> 5;
    float s = 0.f;
    for (int t = g; t < mtiles; t += 32) s += partials[(size_t)t*RD + c];
    red[threadIdx.x] = s;
    __syncthreads();
    #pragma unroll
    for (int off = 512; off >= 32; off >>= 1) {
        if ((int)threadIdx.x < off) red[threadIdx.x] += red[threadIdx.x + off];
        __syncthreads();
    }
    if (threadIdx.x < RD) out[threadIdx.x] = red[threadIdx.x] + (float)n_nodes * b_r2[threadIdx.x];
}

extern "C" void kernel_launch(void* const* d_in, const int* in_sizes, int n_in,
                              void* d_out, int out_size, void* d_ws, size_t ws_size,
                              hipStream_t stream) {
    const float* node_data = (const float*)d_in[0];
    const float* edge_data = (const float*)d_in[1];
    const int*   edge_src  = (const int*)d_in[2];
    const int*   edge_dst  = (const int*)d_in[3];
    const float* W_embed   = (const float*)d_in[4];
    const float* b_embed   = (const float*)d_in[5];
    const float* W_msg     = (const float*)d_in[6];
    const float* b_msg     = (const float*)d_in[7];
    const float* W_i       = (const float*)d_in[8];
    const float* b_i       = (const float*)d_in[9];
    const float* W_h       = (const float*)d_in[10];
    const float* b_h       = (const float*)d_in[11];
    const float* W_r1      = (const float*)d_in[12];
    const float* b_r1      = (const float*)d_in[13];
    const float* W_r2      = (const float*)d_in[14];
    const float* b_r2      = (const float*)d_in[15];

    int n_nodes = in_sizes[0] / VD;    // 20000
    int n_edges = in_sizes[2];         // 320000
    int Lmax = n_edges + n_nodes + 64; // padded CSR capacity
    int mtiles = (n_nodes + 15) / 16;

    char* ws = (char*)d_ws;
    size_t off = 0;
    auto alloc = [&](size_t bytes) {
        void* p = ws + off;
        off = (off + bytes + 255) & ~(size_t)255;
        return p;
    };
    unsigned short* m_accb = (unsigned short*)alloc((size_t)n_nodes * SD * 2);
    unsigned short* hbA = (unsigned short*)alloc((size_t)n_nodes * SD * 2);
    unsigned short* hbB = (unsigned short*)alloc((size_t)n_nodes * SD * 2);
    unsigned short* Ab0 = (unsigned short*)alloc((size_t)n_nodes * SD * 2);
    unsigned short* Bb0 = (unsigned short*)alloc((size_t)n_nodes * SD * 2);
    unsigned short* Ab1 = (unsigned short*)alloc((size_t)n_nodes * SD * 2);
    unsigned short* Bb1 = (unsigned short*)alloc((size_t)n_nodes * SD * 2);
    unsigned short* Cp  = (unsigned short*)alloc((size_t)(Lmax + 32) * SD * 2);
    int*   src_csr      = (int*)alloc((size_t)(Lmax + 96) * sizeof(int));
    int*   row_ptr      = (int*)alloc((size_t)(n_nodes + 1) * sizeof(int));
    int*   perm         = (int*)alloc((size_t)n_nodes * sizeof(int));
    float* partials     = (float*)alloc((size_t)mtiles * RD * sizeof(float));
    // contiguous zero-init region: deg, fillc, eid (one memset)
    char*  zbase        = (char*)alloc(0);
    int*   deg          = (int*)alloc((size_t)n_nodes * sizeof(int));
    int*   fillc        = (int*)alloc((size_t)n_nodes * sizeof(int));
    int*   eid          = (int*)alloc((size_t)(Lmax + 32) * sizeof(int));
    char*  zend         = (char*)alloc(0);
    unsigned short* WabT = (unsigned short*)alloc(128*64*2);
    unsigned short* WiT  = (unsigned short*)alloc(192*64*2);
    unsigned short* WhT  = (unsigned short*)alloc(192*64*2);
    unsigned short* W3T  = (unsigned short*)alloc(64*32*2);
    unsigned short* WeT  = (unsigned short*)alloc(64*32*2);
    (void)ws_size; (void)n_in;

    hipMemsetAsync(zbase, 0, (size_t)(zend - zbase), stream);

    prep_hist_kernel<<<(PREP_N + n_edges + 255)/256, 256, 0, stream>>>(
        W_msg, W_i, W_h, W_embed, WabT, WiT, WhT, W3T, WeT, edge_dst, deg, n_edges);

    scan_kernel<<<1, 1024, 0, stream>>>(deg, row_ptr, perm, n_nodes);

    int fill_blocks = (n_edges + 255)/256;
    fill_embed_kernel<<<fill_blocks + mtiles, 256, 0, stream>>>(
        edge_dst, row_ptr, fillc, eid, n_edges,
        node_data, WeT, b_embed, perm, hbA, WabT, b_msg, Ab0, Bb0, n_nodes, fill_blocks);

    int ec_waves = (Lmax + 15) / 16;
    edgeconst_kernel<<<(ec_waves + 3)/4, 256, 0, stream>>>(eid, edge_src, edge_data, W3T,
                                                           src_csr, Cp, Lmax);

    // it0: read Ab0/Bb0, hbA -> hbB, write Ab1/Bb1
    mpnn_iter_kernel<1,0><<<mtiles, 256, 0, stream>>>(hbA, hbB, Ab0, Bb0, Ab1, Bb1,
        Cp, src_csr, row_ptr, deg, perm, m_accb, WiT, WhT, b_i, b_h, WabT, b_msg,
        W_r1, b_r1, W_r2, partials, n_nodes);
    // it1: read Ab1/Bb1, hbB -> hbA, write Ab0/Bb0
    mpnn_iter_kernel<0,0><<<mtiles, 256, 0, stream>>>(hbB, hbA, Ab1, Bb1, Ab0, Bb0,
        Cp, src_csr, row_ptr, deg, perm, m_accb, WiT, WhT, b_i, b_h, WabT, b_msg,
        W_r1, b_r1, W_r2, partials, n_nodes);
    // it2 (LAST): fused readout partials
    mpnn_iter_kernel<0,1><<<mtiles, 256, 0, stream>>>(hbA, hbB, Ab0, Bb0, Ab1, Bb1,
        Cp, src_csr, row_ptr, deg, perm, m_accb, WiT, WhT, b_i, b_h, WabT, b_msg,
        W_r1, b_r1, W_r2, partials, n_nodes);

    final_sum_kernel<<<1, 1024, 0, stream>>>(partials, b_r2, (float*)d_out, mtiles, n_nodes);
}